// Round 4
// baseline (393.484 us; speedup 1.0000x reference)
//
#include <hip/hip_runtime.h>
#include <hip/hip_bf16.h>

#define D_MODEL 1024
#define NH 8
#define HD 128
#define BATCH 4
#define TSEQ 2048
#define MROWS (BATCH * TSEQ)  // 8192
#define QKV_LD 3072           // fused q|k|v row stride

typedef __attribute__((ext_vector_type(8))) __bf16 bf16x8;
typedef __attribute__((ext_vector_type(4))) __bf16 bf16x4;
typedef __attribute__((ext_vector_type(4))) float f32x4;
typedef __attribute__((ext_vector_type(8))) unsigned short u16x8;

#define SC2 0.1275174441680632f  // (1/sqrt(128)) * log2(e)

__device__ __forceinline__ void gload16(const void* g, void* lds) {
  __builtin_amdgcn_global_load_lds(
      (const __attribute__((address_space(1))) unsigned int*)g,
      (__attribute__((address_space(3))) unsigned int*)lds, 16, 0, 0);
}

// ---------------- small conversion / setup kernels ----------------
__global__ __launch_bounds__(256) void cvt_f32_to_bf16(const float* __restrict__ in,
                                                       __bf16* __restrict__ out, int n4) {
  int i = blockIdx.x * 256 + threadIdx.x;
  if (i < n4) {
    float4 v = reinterpret_cast<const float4*>(in)[i];
    bf16x4 o;
    o[0] = (__bf16)v.x; o[1] = (__bf16)v.y; o[2] = (__bf16)v.z; o[3] = (__bf16)v.w;
    reinterpret_cast<bf16x4*>(out)[i] = o;
  }
}

__global__ __launch_bounds__(256) void cvt4_weights(const float* __restrict__ w0,
                                                    const float* __restrict__ w1,
                                                    const float* __restrict__ w2,
                                                    const float* __restrict__ w3,
                                                    __bf16* __restrict__ out) {
  const int per = D_MODEL * D_MODEL / 4;
  int i = blockIdx.x * 256 + threadIdx.x;
  int m = i / per, j = i - m * per;
  const float* src = (m == 0) ? w0 : (m == 1) ? w1 : (m == 2) ? w2 : w3;
  float4 v = reinterpret_cast<const float4*>(src)[j];
  bf16x4 o;
  o[0] = (__bf16)v.x; o[1] = (__bf16)v.y; o[2] = (__bf16)v.z; o[3] = (__bf16)v.w;
  reinterpret_cast<bf16x4*>(out)[i] = o;
}

__global__ __launch_bounds__(256) void concat_bias(const float* __restrict__ a,
                                                   const float* __restrict__ b,
                                                   const float* __restrict__ c,
                                                   float* __restrict__ o) {
  int i = blockIdx.x * 256 + threadIdx.x;
  if (i < 3072) o[i] = (i < 1024) ? a[i] : (i < 2048) ? b[i - 1024] : c[i - 2048];
}

__global__ __launch_bounds__(256) void invert_lsum(float* __restrict__ L, int n) {
  int i = blockIdx.x * 256 + threadIdx.x;
  if (i < n) L[i] = 1.0f / (8.0f * L[i]);
}

// ---------------- generic 128x128 GEMM:  Y = A @ B^T (+bias), 2-phase dbuf ----
template <bool BF16OUT, bool CAUSAL, bool AFP32>
__global__ __launch_bounds__(256) void gemm128(const void* __restrict__ Aip,
                                               const __bf16* __restrict__ Bp,
                                               const float* __restrict__ bias,
                                               void* __restrict__ Yp, int K, int ldy,
                                               size_t sA, size_t sB, size_t sY) {
  __shared__ __bf16 As[2][128 * 32];
  __shared__ __bf16 Bs[2][128 * 32];
  const int tid = threadIdx.x;
  const int w = tid >> 6, l = tid & 63;
  const int lr = l & 15, lg = l >> 4;
  const int m0 = blockIdx.y * 128, n0 = blockIdx.x * 128;
  const int z = blockIdx.z;
  const __bf16* Ab = AFP32 ? nullptr : (const __bf16*)Aip + z * sA;
  const float* Af = AFP32 ? (const float*)Aip + z * sA : nullptr;
  const __bf16* Bb = Bp + z * sB;
  const int wm = w >> 1, wn = w & 1;
  f32x4 acc[4][4] = {};
  const int Klim = CAUSAL ? (m0 + 128 < K ? m0 + 128 : K) : K;
  const int nt = Klim >> 5;

  auto stage = [&](int t, int buf) {
    const int k0 = t << 5;
    if constexpr (!AFP32) {
#pragma unroll
      for (int i = 0; i < 2; ++i) {
        int s = w * 128 + i * 64 + l;
        int row = s >> 2, scp = s & 3;
        int sc = scp ^ ((row >> 1) & 3);
        gload16(Ab + (size_t)(m0 + row) * K + k0 + sc * 8, (char*)As[buf] + s * 16);
      }
    } else {
#pragma unroll
      for (int i = 0; i < 2; ++i) {
        int s = w * 128 + i * 64 + l;
        int row = s >> 2, sc = s & 3;
        const float* src = Af + (size_t)(m0 + row) * K + k0 + sc * 8;
        float4 lo = *reinterpret_cast<const float4*>(src);
        float4 hi = *reinterpret_cast<const float4*>(src + 4);
        bf16x8 v;
        v[0] = (__bf16)lo.x; v[1] = (__bf16)lo.y; v[2] = (__bf16)lo.z; v[3] = (__bf16)lo.w;
        v[4] = (__bf16)hi.x; v[5] = (__bf16)hi.y; v[6] = (__bf16)hi.z; v[7] = (__bf16)hi.w;
        int p = row * 4 + (sc ^ ((row >> 1) & 3));
        *reinterpret_cast<bf16x8*>((char*)As[buf] + p * 16) = v;
      }
    }
#pragma unroll
    for (int i = 0; i < 2; ++i) {
      int s = w * 128 + i * 64 + l;
      int row = s >> 2, scp = s & 3;
      int sc = scp ^ ((row >> 1) & 3);
      gload16(Bb + (size_t)(n0 + row) * K + k0 + sc * 8, (char*)Bs[buf] + s * 16);
    }
  };

  stage(0, 0);
  __syncthreads();
  int cur = 0;
  for (int t = 0; t < nt; ++t) {
    if (t + 1 < nt) stage(t + 1, cur ^ 1);
    bf16x8 af[4], bf[4];
#pragma unroll
    for (int f = 0; f < 4; ++f) {
      int ar = wm * 64 + f * 16 + lr;
      af[f] = *reinterpret_cast<const bf16x8*>((const char*)As[cur] + ar * 64 +
                                               ((lg ^ ((ar >> 1) & 3)) * 16));
      int br = wn * 64 + f * 16 + lr;
      bf[f] = *reinterpret_cast<const bf16x8*>((const char*)Bs[cur] + br * 64 +
                                               ((lg ^ ((br >> 1) & 3)) * 16));
    }
#pragma unroll
    for (int mf = 0; mf < 4; ++mf)
#pragma unroll
      for (int nf = 0; nf < 4; ++nf)
        acc[mf][nf] = __builtin_amdgcn_mfma_f32_16x16x32_bf16(af[mf], bf[nf], acc[mf][nf], 0, 0, 0);
    __syncthreads();
    cur ^= 1;
  }

#pragma unroll
  for (int mf = 0; mf < 4; ++mf) {
#pragma unroll
    for (int nf = 0; nf < 4; ++nf) {
#pragma unroll
      for (int r = 0; r < 4; ++r) {
        int grow = m0 + wm * 64 + mf * 16 + lg * 4 + r;
        int gcol = n0 + wn * 64 + nf * 16 + lr;
        float v = acc[mf][nf][r];
        if (bias) v += bias[gcol];
        if constexpr (BF16OUT)
          ((__bf16*)Yp + z * sY)[(size_t)grow * ldy + gcol] = (__bf16)v;
        else
          ((float*)Yp + z * sY)[(size_t)grow * ldy + gcol] = v;
      }
    }
  }
}

// ---------------- V[b][t][d] (ld=QKV_LD) -> Vt[b][d][t] ----------------
__global__ __launch_bounds__(256) void transpose_v(const __bf16* __restrict__ V,
                                                   __bf16* __restrict__ Vt) {
  __shared__ unsigned short tile[64 * 72];
  const int b = blockIdx.z;
  const int t0 = blockIdx.x * 64, d0 = blockIdx.y * 64;
  const int tid = threadIdx.x;
#pragma unroll
  for (int i = 0; i < 2; ++i) {
    int s = i * 256 + tid;
    int r = s >> 3, c8 = s & 7;
    u16x8 v = *reinterpret_cast<const u16x8*>(V + ((size_t)b * TSEQ + t0 + r) * QKV_LD + d0 + c8 * 8);
    *reinterpret_cast<u16x8*>(&tile[r * 72 + c8 * 8]) = v;
  }
  __syncthreads();
#pragma unroll
  for (int i = 0; i < 2; ++i) {
    int s = i * 256 + tid;
    int dr = s >> 3, t8 = s & 7;
    u16x8 o;
#pragma unroll
    for (int j = 0; j < 8; ++j) o[j] = tile[(t8 * 8 + j) * 72 + dr];
    *reinterpret_cast<u16x8*>(Vt + ((size_t)b * D_MODEL + d0 + dr) * TSEQ + t0 + t8 * 8) = o;
  }
}

// ---- [128][128] bf16 tile staging, 512 threads; phys_seg = log_seg ^ (row&15)
__device__ __forceinline__ void stage_tile128(const __bf16* __restrict__ src,
                                              __bf16* __restrict__ dst, int tid, int ld) {
#pragma unroll
  for (int i = 0; i < 4; ++i) {
    int s = i * 512 + tid;  // 2048 16B segs
    int row = s >> 4, sp = s & 15;
    int sl = sp ^ (row & 15);
    gload16(src + (size_t)row * ld + sl * 8, (char*)dst + s * 16);
  }
}

__device__ __forceinline__ bf16x8 ldfrag(const __bf16* t, int row, int c, int lg) {
  return *reinterpret_cast<const bf16x8*>((const char*)t + row * 256 +
                                          (((c * 4 + lg) ^ (row & 15)) * 16));
}

// ---------------- attention core: 128x128 tile, 8 waves, head-looped --------
// MODE 0: Lsum partials via atomicAdd.  MODE 1: alpha = sum_h exp*Linv (+zero-fill).
template <int MODE>
__global__ __launch_bounds__(512) void attn128(const __bf16* __restrict__ QKV,
                                               const float* __restrict__ Linv,
                                               float* __restrict__ Out) {
  const int kt = blockIdx.x, qt = blockIdx.y, b = blockIdx.z;
  const int tid = threadIdx.x;
  const int q0 = qt * 128, k0 = kt * 128;
  if (kt > qt) {
    if (MODE == 1) {
      float4 zz = {0.f, 0.f, 0.f, 0.f};
#pragma unroll
      for (int i = 0; i < 8; ++i) {
        int s = i * 512 + tid;  // 4096 float4s
        int row = s >> 5, c = s & 31;
        *reinterpret_cast<float4*>(Out + ((size_t)(b * TSEQ) + q0 + row) * TSEQ + k0 + c * 4) = zz;
      }
    }
    return;
  }
  __shared__ __bf16 Qs[2][128 * 128];
  __shared__ __bf16 Ks[2][128 * 128];
  const int w = tid >> 6, l = tid & 63;
  const int lr = l & 15, lg = l >> 4;
  const int wq = w >> 1;  // 0..3 : 32-row quadrant
  const int wk = w & 1;   // 0..1 : 64-col half
  const __bf16* qb0 = QKV + (size_t)(b * TSEQ + q0) * QKV_LD;         // Q cols 0..1023
  const __bf16* kb0 = QKV + (size_t)(b * TSEQ + k0) * QKV_LD + 1024;  // K cols

  stage_tile128(qb0, Qs[0], tid, QKV_LD);
  stage_tile128(kb0, Ks[0], tid, QKV_LD);
  __syncthreads();

  float outv[2][4][4] = {};
  int cur = 0;
  for (int h = 0; h < NH; ++h) {
    if (h + 1 < NH) {
      stage_tile128(qb0 + (h + 1) * HD, Qs[cur ^ 1], tid, QKV_LD);
      stage_tile128(kb0 + (h + 1) * HD, Ks[cur ^ 1], tid, QKV_LD);
    }
    bf16x8 af[2][4], bf[4][4];
#pragma unroll
    for (int mf = 0; mf < 2; ++mf)
#pragma unroll
      for (int c = 0; c < 4; ++c) af[mf][c] = ldfrag(Qs[cur], wq * 32 + mf * 16 + lr, c, lg);
#pragma unroll
    for (int nf = 0; nf < 4; ++nf)
#pragma unroll
      for (int c = 0; c < 4; ++c) bf[nf][c] = ldfrag(Ks[cur], wk * 64 + nf * 16 + lr, c, lg);
    f32x4 acc[2][4] = {};
#pragma unroll
    for (int c = 0; c < 4; ++c)
#pragma unroll
      for (int mf = 0; mf < 2; ++mf)
#pragma unroll
        for (int nf = 0; nf < 4; ++nf)
          acc[mf][nf] = __builtin_amdgcn_mfma_f32_16x16x32_bf16(af[mf][c], bf[nf][c], acc[mf][nf], 0, 0, 0);

    if constexpr (MODE == 0) {
      float ls[2][4] = {};
#pragma unroll
      for (int mf = 0; mf < 2; ++mf)
#pragma unroll
        for (int nf = 0; nf < 4; ++nf)
#pragma unroll
          for (int r = 0; r < 4; ++r) {
            int q = q0 + wq * 32 + mf * 16 + lg * 4 + r;
            int k = k0 + wk * 64 + nf * 16 + lr;
            if (kt < qt || k <= q) ls[mf][r] += exp2f(acc[mf][nf][r] * SC2);
          }
#pragma unroll
      for (int m = 1; m < 16; m <<= 1)
#pragma unroll
        for (int mf = 0; mf < 2; ++mf)
#pragma unroll
          for (int r = 0; r < 4; ++r) ls[mf][r] += __shfl_xor(ls[mf][r], m, 64);
      if (lr == 0) {
#pragma unroll
        for (int mf = 0; mf < 2; ++mf)
#pragma unroll
          for (int r = 0; r < 4; ++r)
            atomicAdd(&Out[((size_t)(b * NH + h)) * TSEQ + q0 + wq * 32 + mf * 16 + lg * 4 + r],
                      ls[mf][r]);
      }
    } else {
      float4 li[2];
#pragma unroll
      for (int mf = 0; mf < 2; ++mf)
        li[mf] = *reinterpret_cast<const float4*>(
            &Linv[((size_t)(b * NH + h)) * TSEQ + q0 + wq * 32 + mf * 16 + lg * 4]);
#pragma unroll
      for (int mf = 0; mf < 2; ++mf)
#pragma unroll
        for (int nf = 0; nf < 4; ++nf)
#pragma unroll
          for (int r = 0; r < 4; ++r) {
            int q = q0 + wq * 32 + mf * 16 + lg * 4 + r;
            int k = k0 + wk * 64 + nf * 16 + lr;
            if (kt < qt || k <= q)
              outv[mf][nf][r] += exp2f(acc[mf][nf][r] * SC2) * (&li[mf].x)[r];
          }
    }
    __syncthreads();
    cur ^= 1;
  }
  if constexpr (MODE == 1) {
#pragma unroll
    for (int mf = 0; mf < 2; ++mf)
#pragma unroll
      for (int nf = 0; nf < 4; ++nf)
#pragma unroll
        for (int r = 0; r < 4; ++r)
          Out[((size_t)(b * TSEQ) + q0 + wq * 32 + mf * 16 + lg * 4 + r) * TSEQ +
              k0 + wk * 64 + nf * 16 + lr] = outv[mf][nf][r];
  }
}

extern "C" void kernel_launch(void* const* d_in, const int* in_sizes, int n_in,
                              void* d_out, int out_size, void* d_ws, size_t ws_size,
                              hipStream_t stream) {
  const float* x  = (const float*)d_in[0];
  const float* Wq = (const float*)d_in[2];
  const float* bq = (const float*)d_in[3];
  const float* Wk = (const float*)d_in[4];
  const float* bk = (const float*)d_in[5];
  const float* Wv = (const float*)d_in[6];
  const float* bv = (const float*)d_in[7];
  const float* Wo = (const float*)d_in[8];
  const float* bo = (const float*)d_in[9];

  float* out_f = (float*)d_out;                    // [4,2048,1024]
  float* alpha = out_f + (size_t)MROWS * D_MODEL;  // [4,2048,2048]

  char* p = (char*)d_ws;
  __bf16* xb   = (__bf16*)p; p += (size_t)MROWS * D_MODEL * 2;      // reused as midb
  __bf16* wqb  = (__bf16*)p; p += (size_t)D_MODEL * D_MODEL * 2;    // wq|wk|wv|wo contiguous
  __bf16* wkb  = (__bf16*)p; p += (size_t)D_MODEL * D_MODEL * 2;
  __bf16* wvb  = (__bf16*)p; p += (size_t)D_MODEL * D_MODEL * 2;
  __bf16* wob  = (__bf16*)p; p += (size_t)D_MODEL * D_MODEL * 2;
  __bf16* qkv  = (__bf16*)p; p += (size_t)MROWS * QKV_LD * 2;       // 48 MB
  __bf16* vtb  = (__bf16*)p; p += (size_t)BATCH * D_MODEL * TSEQ * 2;
  float* lsum  = (float*)p;  p += (size_t)BATCH * NH * TSEQ * 4;
  float* bcat  = (float*)p;  p += 3072 * 4;
  __bf16* midb = xb;

  // 0) zero the atomic Lsum accumulator
  hipMemsetAsync(lsum, 0, (size_t)BATCH * NH * TSEQ * 4, stream);

  // 1) conversions + bias concat
  {
    int n4 = MROWS * D_MODEL / 4;
    cvt_f32_to_bf16<<<n4 / 256, 256, 0, stream>>>(x, xb, n4);
    int w4 = 4 * D_MODEL * D_MODEL / 4;
    cvt4_weights<<<w4 / 256, 256, 0, stream>>>(Wq, Wk, Wv, Wo, wqb);
    concat_bias<<<12, 256, 0, stream>>>(bq, bk, bv, bcat);
  }

  // 2) fused QKV projection: [8192x1024] @ [3072x1024]^T -> qkv[8192][3072]
  gemm128<true, false, false><<<dim3(QKV_LD / 128, MROWS / 128), 256, 0, stream>>>(
      xb, wqb, bcat, qkv, D_MODEL, QKV_LD, 0, 0, 0);

  // 3) V transpose (V = qkv cols 2048..3071)
  transpose_v<<<dim3(TSEQ / 64, D_MODEL / 64, BATCH), 256, 0, stream>>>(qkv + 2048, vtb);

  // 4) stats: Lsum partials (atomic), then invert
  attn128<0><<<dim3(TSEQ / 128, TSEQ / 128, BATCH), 512, 0, stream>>>(qkv, nullptr, lsum);
  invert_lsum<<<(BATCH * NH * TSEQ) / 256, 256, 0, stream>>>(lsum, BATCH * NH * TSEQ);

  // 5) head-averaged attention -> alpha
  attn128<1><<<dim3(TSEQ / 128, TSEQ / 128, BATCH), 512, 0, stream>>>(qkv, lsum, alpha);

  // 6) Mid = alpha @ V
  gemm128<true, true, true><<<dim3(D_MODEL / 128, TSEQ / 128, BATCH), 256, 0, stream>>>(
      alpha, vtb, nullptr, midb, TSEQ, D_MODEL,
      (size_t)TSEQ * TSEQ, (size_t)D_MODEL * TSEQ, (size_t)TSEQ * D_MODEL);

  // 7) out = Mid @ Wo^T + bo
  gemm128<false, false, false><<<dim3(D_MODEL / 128, MROWS / 128), 256, 0, stream>>>(
      midb, wob, bo, out_f, D_MODEL, D_MODEL, 0, 0, 0);
}